// Round 15
// baseline (78.737 us; speedup 1.0000x reference)
//
#include <hip/hip_runtime.h>

#define K_BINS 1025
#define T_LEN  2000
#define NF     128
#define TH     1000   // t per block (2000 = 2*1000) -> 4 KB row-reads
#define THQ    250    // float4 per th-slice
#define ROWQ   500    // float4 per full k-row

__device__ __forceinline__ float softplusf(float x) {
    // matches jax.nn.softplus = max(x,0) + log1p(exp(-|x|))
    return fmaxf(x, 0.0f) + log1pf(expf(-fabsf(x)));
}

// out[b2][t][4*bp + w] = sum_k w_f(k) * spec[bp][k][t],  f = b2 + 32*w
// Block = (q, hp, B, th): bp-pair {4q+2hp, +1}, b2-quad B, t-half th.
// 512 thr = 8 waves. Wave wid -> (j = wid>>2, w = j ? 3-(wid&3) : wid&3):
// quad (B,w) for bp = 4q+2hp+j. The w<->3-w pairing balances SIMD loads
// (w-unions ~19/24/36/60 rows -> per-SIMD 79/60 instead of 60/17).
// DRAM granularity: 4 KB per row-read (vs R7/R14's 2 KB -> ~4.9 TB/s,
// vs R4's 8 KB -> 6.2 TB/s measured). The grid (8,2,16) is exactly
// 1 block/CU, all co-resident; id%8 = q pins each bp-quad to one XCD, so
// the th-sibling (other 4 KB of the same rows) and hp-sibling (other 32 B
// of each out line) run simultaneously there: DRAM page gets both row
// halves, L2 merges the write halves into full 64 B lines.
// Inner loop: R14's merged-run walk in static 4-row chunks (16 independent
// loads in flight; wave-uniform k<=ke masks run pads + top boundary).
// __launch_bounds__(512,2) -> 256-VGPR budget: no 64-VGPR spill heuristic.
__global__ __launch_bounds__(512, 2) void fb_fused(
        const float* __restrict__ spec,
        const float* __restrict__ cf,
        const float* __restrict__ bwv,
        const float* __restrict__ fs,
        float*       __restrict__ out) {
    __shared__ __align__(16) float tile[8][1004];   // 32 KB

    const int q    = blockIdx.x;        // 0..7 (id%8 -> XCD q)
    const int hp   = blockIdx.y;        // bp-pair half 0..1
    const int B    = blockIdx.z >> 1;   // b2-quad 0..7
    const int th   = blockIdx.z & 1;    // t-half 0..1
    const int tid  = threadIdx.x;
    const int lane = tid & 63;
    const int wid  = tid >> 6;          // 0..7
    const int j    = wid >> 2;          // bp-local 0..1
    const int s    = wid & 3;
    const int w    = j ? (3 - s) : s;   // SIMD-balanced band pairing
    const int bp   = 4 * q + 2 * hp + j;
    const int t0   = TH * th;
    const bool ok3 = lane < (THQ - 192);        // m=3 live (lane < 58)
    const int  li3 = min(192 + lane, THQ - 1);  // clamped: in-bounds

    const float4* base4 =
        (const float4*)(spec + (size_t)bp * (K_BINS * (size_t)T_LEN) + t0);

    // ---- params for the 4 adjacent filters of band w, quad B ----
    float ic[4], mir[4], mA[4], Bfc[4];
    int   klo4[4], khi4[4];
#pragma unroll
    for (int i = 0; i < 4; ++i) {
        const int f = 4 * B + 32 * w + i;
        float c  = cf[f];
        float bw = softplusf(bwv[f]) + 0.001f;
        float s0 = softplusf(fs[2 * f])     + 0.1f;
        float s1 = softplusf(fs[2 * f + 1]) + 0.1f;
        float left  = c - bw * s0;
        float right = c + bw * s1;
        float icv = 1.0f / (c - left + 1e-8f);
        float irv = 1.0f / (right - c + 1e-8f);
        ic[i]  = icv;
        mir[i] = -irv;
        mA[i]  = -left * icv;           // rise = fk*ic + mA
        Bfc[i] = fmaf(c, irv, 1.0f);    // fall = fk*mir + Bfc
        klo4[i] = max(0, (int)ceilf(left));
        khi4[i] = min(K_BINS - 1, (int)floorf(right));
    }

    // ---- merge the 4 ascending intervals into <=4 runs (named scalars) ----
    int RS0 = klo4[0], RE0 = khi4[0];
    int RS1 = 0, RE1 = -1, RS2 = 0, RE2 = -1, RS3 = 0, RE3 = -1;
    int nr = 1;
#pragma unroll
    for (int i = 1; i < 4; ++i) {
        const int ss = klo4[i], e = khi4[i];
        const int le = (nr == 1) ? RE0 : (nr == 2) ? RE1 : RE2;
        if (ss <= le + 1) {
            const int ne = max(le, e);
            if (nr == 1) RE0 = ne; else if (nr == 2) RE1 = ne; else RE2 = ne;
        } else {
            if (nr == 1)      { RS1 = ss; RE1 = e; }
            else if (nr == 2) { RS2 = ss; RE2 = e; }
            else              { RS3 = ss; RE3 = e; }
            ++nr;
        }
    }

    float4 acc[4][4];              // [filter i][m]
#pragma unroll
    for (int i = 0; i < 4; ++i)
#pragma unroll
        for (int m = 0; m < 4; ++m) acc[i][m] = make_float4(0.f, 0.f, 0.f, 0.f);

#define ROWSTEP(KK, V0, V1, V2, V3)                                         \
    { const int   k_  = (KK);                                               \
      const float fk_ = (float)k_;                                          \
      const bool  lv_ = (k_ <= ke);   /* masks run pads + top boundary */   \
      _Pragma("unroll")                                                     \
      for (int i = 0; i < 4; ++i) {                                         \
          float wg = fmaxf(0.0f, fminf(fmaf(fk_, ic[i],  mA[i]),            \
                                       fmaf(fk_, mir[i], Bfc[i])));         \
          wg = lv_ ? wg : 0.0f;                                             \
          acc[i][0].x = fmaf(wg, V0.x, acc[i][0].x);                        \
          acc[i][0].y = fmaf(wg, V0.y, acc[i][0].y);                        \
          acc[i][0].z = fmaf(wg, V0.z, acc[i][0].z);                        \
          acc[i][0].w = fmaf(wg, V0.w, acc[i][0].w);                        \
          acc[i][1].x = fmaf(wg, V1.x, acc[i][1].x);                        \
          acc[i][1].y = fmaf(wg, V1.y, acc[i][1].y);                        \
          acc[i][1].z = fmaf(wg, V1.z, acc[i][1].z);                        \
          acc[i][1].w = fmaf(wg, V1.w, acc[i][1].w);                        \
          acc[i][2].x = fmaf(wg, V2.x, acc[i][2].x);                        \
          acc[i][2].y = fmaf(wg, V2.y, acc[i][2].y);                        \
          acc[i][2].z = fmaf(wg, V2.z, acc[i][2].z);                        \
          acc[i][2].w = fmaf(wg, V2.w, acc[i][2].w);                        \
          acc[i][3].x = fmaf(wg, V3.x, acc[i][3].x);                        \
          acc[i][3].y = fmaf(wg, V3.y, acc[i][3].y);                        \
          acc[i][3].z = fmaf(wg, V3.z, acc[i][3].z);                        \
          acc[i][3].w = fmaf(wg, V3.w, acc[i][3].w);                        \
      } }

#pragma unroll
    for (int r = 0; r < 4; ++r) {
        int ks, ke;
        if      (r == 0) { ks = RS0; ke = RE0; }
        else if (r == 1) { ks = RS1; ke = RE1; }
        else if (r == 2) { ks = RS2; ke = RE2; }
        else             { ks = RS3; ke = RE3; }
        for (int k0 = ks; k0 <= ke; k0 += 4) {      // 4-row static body
            const float4* rp0 = base4 + (size_t)min(k0,     K_BINS - 1) * ROWQ;
            const float4* rp1 = base4 + (size_t)min(k0 + 1, K_BINS - 1) * ROWQ;
            const float4* rp2 = base4 + (size_t)min(k0 + 2, K_BINS - 1) * ROWQ;
            const float4* rp3 = base4 + (size_t)min(k0 + 3, K_BINS - 1) * ROWQ;
            float4 a00 = rp0[lane], a01 = rp0[64 + lane], a02 = rp0[128 + lane], a03 = rp0[li3];
            float4 a10 = rp1[lane], a11 = rp1[64 + lane], a12 = rp1[128 + lane], a13 = rp1[li3];
            float4 a20 = rp2[lane], a21 = rp2[64 + lane], a22 = rp2[128 + lane], a23 = rp2[li3];
            float4 a30 = rp3[lane], a31 = rp3[64 + lane], a32 = rp3[128 + lane], a33 = rp3[li3];
            ROWSTEP(k0 + 0, a00, a01, a02, a03);
            ROWSTEP(k0 + 1, a10, a11, a12, a13);
            ROWSTEP(k0 + 2, a20, a21, a22, a23);
            ROWSTEP(k0 + 3, a30, a31, a32, a33);
        }
    }
#undef ROWSTEP

    // ---- Epilogue: per filter i, col-major LDS transpose; stores are 32 B
    // segments whose sibling half comes from the co-resident hp-block ->
    // L2 line-merge.
    const int col = 4 * j + w;          // f2 - (16q + 8hp)
#pragma unroll
    for (int i = 0; i < 4; ++i) {
        __syncthreads();                // protect tile reuse
        *reinterpret_cast<float4*>(&tile[col][4 * lane])       = acc[i][0];
        *reinterpret_cast<float4*>(&tile[col][256 + 4 * lane]) = acc[i][1];
        *reinterpret_cast<float4*>(&tile[col][512 + 4 * lane]) = acc[i][2];
        if (ok3)
            *reinterpret_cast<float4*>(&tile[col][768 + 4 * lane]) = acc[i][3];
        __syncthreads();
        const int b2 = 4 * B + i;
        const int c4 = tid & 1;
#pragma unroll
        for (int rr = 0; rr < 4; ++rr) {
            int tl = 256 * rr + (tid >> 1);
            if (tl < TH) {
                float4 v = make_float4(tile[4 * c4 + 0][tl], tile[4 * c4 + 1][tl],
                                       tile[4 * c4 + 2][tl], tile[4 * c4 + 3][tl]);
                *reinterpret_cast<float4*>(
                    out + ((size_t)b2 * T_LEN + t0 + tl) * NF
                        + 16 * q + 8 * hp + 4 * c4) = v;
            }
        }
    }
}

extern "C" void kernel_launch(void* const* d_in, const int* in_sizes, int n_in,
                              void* d_out, int out_size, void* d_ws, size_t ws_size,
                              hipStream_t stream) {
    const float* spec = (const float*)d_in[0];   // (32, 1025, 2000) f32
    const float* cf   = (const float*)d_in[1];   // (128,)
    const float* bwv  = (const float*)d_in[2];   // (128,)
    const float* fs   = (const float*)d_in[3];   // (128, 2)
    float* out = (float*)d_out;                  // (32, 2000, 128) f32

    fb_fused<<<dim3(8, 2, 16), 512, 0, stream>>>(spec, cf, bwv, fs, out);
}